// Round 1
// baseline (452.266 us; speedup 1.0000x reference)
//
#include <hip/hip_runtime.h>

#define T_    1024
#define H_    1024
#define IDIM  1024
#define E_    16
#define TOPK  4
#define ALPHA 1.702f
#define LIMIT 7.0f

typedef __bf16 bf16;
typedef __bf16 bf16x4 __attribute__((ext_vector_type(4)));
typedef __bf16 bf16x8 __attribute__((ext_vector_type(8)));
typedef float  f32x4  __attribute__((ext_vector_type(4)));

// ---------------------------------------------------------------------------
// Kernel 1: RMSNorm + router logits + softmax/top-4 + routing lists.
// ---------------------------------------------------------------------------
__global__ __launch_bounds__(256) void k_rms_router(
    const float* __restrict__ x, const float* __restrict__ nw,
    const float* __restrict__ rw, const float* __restrict__ rb,
    const float* __restrict__ mw, const int* __restrict__ lidx,
    bf16* __restrict__ tB, float* __restrict__ out,
    int* __restrict__ cnt, int* __restrict__ tok_list,
    float* __restrict__ wgt_list)
{
    const int t = blockIdx.x, tid = threadIdx.x;
    const int lane = tid & 63, wave = tid >> 6;
    __shared__ float tbuf[H_];
    __shared__ float red[4];
    __shared__ float logits[E_];

    float4 xv = ((const float4*)(x + (size_t)t * H_))[tid];
    float4 wv = ((const float4*)nw)[tid];
    float ssq = xv.x*xv.x + xv.y*xv.y + xv.z*xv.z + xv.w*xv.w;
    #pragma unroll
    for (int off = 32; off; off >>= 1) ssq += __shfl_xor(ssq, off);
    if (lane == 0) red[wave] = ssq;
    __syncthreads();
    const float rms = rsqrtf((red[0] + red[1] + red[2] + red[3]) * (1.0f / H_) + 1e-5f);

    float4 tv;
    tv.x = xv.x * rms * wv.x;
    tv.y = xv.y * rms * wv.y;
    tv.z = xv.z * rms * wv.z;
    tv.w = xv.w * rms * wv.w;

    ((float4*)(out + (size_t)t * H_))[tid] = xv;      // residual init
    ((float4*)tbuf)[tid] = tv;
    bf16x4 tb = { (bf16)tv.x, (bf16)tv.y, (bf16)tv.z, (bf16)tv.w };
    *(bf16x4*)(tB + (size_t)t * H_ + tid * 4) = tb;
    __syncthreads();

    #pragma unroll
    for (int ei = 0; ei < 4; ++ei) {
        const int e = wave * 4 + ei;
        const float* wr = rw + (size_t)e * H_;
        float s = 0.f;
        #pragma unroll
        for (int j = 0; j < 16; ++j) {
            const int c = lane + j * 64;
            s += tbuf[c] * wr[c];
        }
        #pragma unroll
        for (int off = 32; off; off >>= 1) s += __shfl_xor(s, off);
        if (lane == 0) logits[e] = s + rb[e];
    }
    __syncthreads();

    if (tid == 0) {
        float g[E_];
        #pragma unroll
        for (int e = 0; e < E_; ++e) g[e] = logits[e];

        const int li = lidx[0];
        float ma = 0.f, lw[E_];
        #pragma unroll
        for (int e = 0; e < E_; ++e) { lw[e] = mw[li * E_ + e]; ma = fmaxf(ma, fabsf(lw[e])); }
        if (ma > 0.f) {
            float mx = -1e30f;
            for (int e = 0; e < E_; ++e) mx = fmaxf(mx, g[e]);
            float se = 0.f;
            for (int e = 0; e < E_; ++e) se += expf(g[e] - mx);
            const float lse = logf(se) + mx;
            float gl[E_], gmx = -1e30f, gmn = 1e30f;
            for (int e = 0; e < E_; ++e) { gl[e] = g[e] - lse; gmx = fmaxf(gmx, gl[e]); gmn = fminf(gmn, gl[e]); }
            for (int e = 0; e < E_; ++e) {
                if (lw[e] > 0.f)      gl[e] = gmx + 0.01f;
                else if (lw[e] < 0.f) gl[e] = gmn - 0.01f;
                g[e] = gl[e];
            }
        }

        float mx = -1e30f;
        #pragma unroll
        for (int e = 0; e < E_; ++e) mx = fmaxf(mx, g[e]);
        float p[E_];
        #pragma unroll
        for (int e = 0; e < E_; ++e) p[e] = expf(g[e] - mx);

        bool used[E_] = {};
        int   idx[TOPK];
        float twv[TOPK];
        float ssum = 0.f;
        for (int k = 0; k < TOPK; ++k) {
            int best = -1; float bv = -1e30f;
            for (int e = 0; e < E_; ++e)
                if (!used[e] && p[e] > bv) { bv = p[e]; best = e; }
            used[best] = true; idx[k] = best; twv[k] = bv; ssum += bv;
        }
        const float inv = 1.f / ssum;
        for (int k = 0; k < TOPK; ++k) {
            const int e = idx[k];
            const int slot = atomicAdd(&cnt[e], 1);
            tok_list[e * T_ + slot] = t;
            wgt_list[e * T_ + slot] = twv[k] * inv;
        }
    }
}

// ---------------------------------------------------------------------------
// Kernel 2: scan + tile table — wave-parallel (was single-thread serial,
// ~100 dependent global ops; now ~20 latency-chained ops).
// ---------------------------------------------------------------------------
__global__ void k_scan(const int* __restrict__ cnt, int* __restrict__ base,
                       int* __restrict__ tiln, int* __restrict__ tile_e,
                       int* __restrict__ tile_m0)
{
    const int lane = threadIdx.x;            // 64 threads, lanes 0..15 active
    int c = (lane < E_) ? cnt[lane] : 0;

    // inclusive scan of counts over 16 lanes
    int s = c;
    #pragma unroll
    for (int off = 1; off < 16; off <<= 1) {
        int tv = __shfl_up(s, off);
        if ((lane & 15) >= off) s += tv;
    }
    if (lane < E_) base[lane] = s - c;       // exclusive prefix
    if (lane == E_ - 1) base[E_] = s;

    // inclusive scan of tile counts
    int nt = (lane < E_) ? ((c + 63) >> 6) : 0;
    int ts = nt;
    #pragma unroll
    for (int off = 1; off < 16; off <<= 1) {
        int tv = __shfl_up(ts, off);
        if ((lane & 15) >= off) ts += tv;
    }
    if (lane == E_ - 1) tiln[0] = ts;
    if (lane < E_) {
        const int t0 = ts - nt;
        for (int i = 0; i < nt; ++i) {
            if (t0 + i < 96) { tile_e[t0 + i] = lane; tile_m0[t0 + i] = i * 64; }
        }
    }
}

// ---------------------------------------------------------------------------
// Kernel 3: grouped gate_up GEMM. A staged in LDS in fragment order, B
// gathered register-direct from the ORIGINAL fp32 weights (fp32->bf16 cast
// in-register; exact same element mapping the repack kernel produced, so
// numerics are identical). No repack pass. BM=64, BK=64, 16 k-steps,
// 1-deep register double-buffer, final iteration peeled (no OOB prefetch).
// grid: (16, 80); wave w handles gate nb = bx*4+w and up nb = gate+64.
// ---------------------------------------------------------------------------
__global__ __launch_bounds__(256) void k_gateup4(
    const bf16* __restrict__ tB, const float* __restrict__ w13,
    const float* __restrict__ b13, const int* __restrict__ cnt,
    const int* __restrict__ base, const int* __restrict__ tiln,
    const int* __restrict__ tile_e, const int* __restrict__ tile_m0,
    const int* __restrict__ tok_list, bf16* __restrict__ act)
{
    const int ti = blockIdx.y;
    if (ti >= tiln[0]) return;
    const int e  = tile_e[ti];
    const int m0 = tile_m0[ti];
    const int ne = cnt[e];

    const int tid = threadIdx.x, lane = tid & 63, wave = tid >> 6;
    const int q = lane >> 4, r = lane & 15;

    __shared__ __align__(16) bf16 As[8 * 64 * 8];

    const int m   = tid >> 2, kq = tid & 3;
    const int mf_s = m >> 4, r_s = m & 15;
    const int kc_s = kq >> 1, q_s = (kq & 1) * 2;
    bf16* wr0 = As + ((size_t)((mf_s * 2 + kc_s) * 64 + q_s * 16 + r_s)) * 8;
    bf16* wr1 = wr0 + 16 * 8;
    int srow = m0 + m; srow = srow < ne ? srow : ne - 1;
    const bf16* pA = tB + (size_t)tok_list[e * T_ + srow] * H_ + kq * 16;

    const int nb_g = blockIdx.x * 4 + wave;
    const size_t wrow = 2 * IDIM;
    // fragment element j of (lane, kc): W13[e][k0 + kc*32 + q*8 + j][nb*16 + r]
    const float* pBg = w13 + (size_t)e * H_ * wrow + (size_t)(q * 8) * wrow
                           + (size_t)nb_g * 16 + r;
    const float* pBu = pBg + IDIM;

    f32x4 accg[4] = {};
    f32x4 accu[4] = {};
    uint4 ar0a, ar0b, ar1a, ar1b;
    bf16x8 bg0[2], bu0[2], bg1[2], bu1[2];

#define LOADA(A0, A1) do { \
    A0 = *(const uint4*)pA; A1 = *(const uint4*)(pA + 8); pA += 64; } while (0)
#define STAGEA(A0, A1) do { \
    *(uint4*)wr0 = A0; *(uint4*)wr1 = A1; } while (0)
#define LOADB(BG, BU) do { \
    _Pragma("unroll") \
    for (int j = 0; j < 8; ++j) { \
        BG[0][j] = (bf16)pBg[(size_t)j * wrow]; \
        BG[1][j] = (bf16)pBg[(size_t)(j + 32) * wrow]; \
        BU[0][j] = (bf16)pBu[(size_t)j * wrow]; \
        BU[1][j] = (bf16)pBu[(size_t)(j + 32) * wrow]; \
    } \
    pBg += 64 * wrow; pBu += 64 * wrow; } while (0)
#define COMPUTE(BG, BU) do { \
    _Pragma("unroll") \
    for (int kc = 0; kc < 2; ++kc) { \
        bf16x8 afr[4]; \
        _Pragma("unroll") \
        for (int mf = 0; mf < 4; ++mf) \
            afr[mf] = *(const bf16x8*)(As + ((size_t)((mf * 2 + kc) * 64 + lane)) * 8); \
        _Pragma("unroll") \
        for (int mf = 0; mf < 4; ++mf) { \
            accg[mf] = __builtin_amdgcn_mfma_f32_16x16x32_bf16(afr[mf], BG[kc], accg[mf], 0, 0, 0); \
            accu[mf] = __builtin_amdgcn_mfma_f32_16x16x32_bf16(afr[mf], BU[kc], accu[mf], 0, 0, 0); \
        } \
    } } while (0)

    LOADA(ar0a, ar0b);
    LOADB(bg0, bu0);
    #pragma unroll 1
    for (int kb = 0; kb < 14; kb += 2) {
        __syncthreads();
        STAGEA(ar0a, ar0b);
        LOADA(ar1a, ar1b);
        LOADB(bg1, bu1);
        __syncthreads();
        COMPUTE(bg0, bu0);

        __syncthreads();
        STAGEA(ar1a, ar1b);
        LOADA(ar0a, ar0b);
        LOADB(bg0, bu0);
        __syncthreads();
        COMPUTE(bg1, bu1);
    }
    // peeled final two k-steps (k = 896..1023): no out-of-bounds prefetch
    __syncthreads();
    STAGEA(ar0a, ar0b);
    LOADA(ar1a, ar1b);
    LOADB(bg1, bu1);
    __syncthreads();
    COMPUTE(bg0, bu0);

    __syncthreads();
    STAGEA(ar1a, ar1b);
    __syncthreads();
    COMPUTE(bg1, bu1);
#undef LOADA
#undef STAGEA
#undef LOADB
#undef COMPUTE

    // --- epilogue ---
    const int sb = base[e];
    const int cg = nb_g * 16 + r;                 // column in [0, IDIM)
    const float bgv = b13[e * 2 * IDIM + cg];
    const float buv = b13[e * 2 * IDIM + IDIM + cg];
    #pragma unroll
    for (int mf = 0; mf < 4; ++mf) {
        #pragma unroll
        for (int rg = 0; rg < 4; ++rg) {
            const int row = mf * 16 + q * 4 + rg;
            if (m0 + row < ne) {
                const float hg = accg[mf][rg] + bgv;
                const float hu = accu[mf][rg] + buv;
                const float gt = fminf(hg, LIMIT);
                const float up = fminf(fmaxf(hu, -LIMIT), LIMIT);
                const float av = (up + 1.0f) * gt / (1.0f + expf(-ALPHA * gt));
                act[(size_t)(sb + m0 + row) * IDIM + cg] = (bf16)av;
            }
        }
    }
}

// ---------------------------------------------------------------------------
// Kernel 4: grouped down GEMM + weighted atomic combine. Same direct-fp32
// B gather. grid: (8, 80); wave w handles nb = bx*8 + w*2 + {0,1}.
// ---------------------------------------------------------------------------
__global__ __launch_bounds__(256) void k_down4(
    const bf16* __restrict__ act, const float* __restrict__ w2,
    const float* __restrict__ b2, const int* __restrict__ cnt,
    const int* __restrict__ base, const int* __restrict__ tiln,
    const int* __restrict__ tile_e, const int* __restrict__ tile_m0,
    const int* __restrict__ tok_list, const float* __restrict__ wgt_list,
    float* __restrict__ out)
{
    const int ti = blockIdx.y;
    if (ti >= tiln[0]) return;
    const int e  = tile_e[ti];
    const int m0 = tile_m0[ti];
    const int ne = cnt[e];
    const int sb = base[e];

    const int tid = threadIdx.x, lane = tid & 63, wave = tid >> 6;
    const int q = lane >> 4, r = lane & 15;

    __shared__ __align__(16) bf16 As[8 * 64 * 8];

    const int m   = tid >> 2, kq = tid & 3;
    const int mf_s = m >> 4, r_s = m & 15;
    const int kc_s = kq >> 1, q_s = (kq & 1) * 2;
    bf16* wr0 = As + ((size_t)((mf_s * 2 + kc_s) * 64 + q_s * 16 + r_s)) * 8;
    bf16* wr1 = wr0 + 16 * 8;
    int srow = m0 + m; srow = srow < ne ? srow : ne - 1;
    const bf16* pA = act + (size_t)(sb + srow) * IDIM + kq * 16;

    const int nb0 = blockIdx.x * 8 + wave * 2;
    // fragment element j of (lane, kc): W2[e][k0 + kc*32 + q*8 + j][nb*16 + r]
    const float* pB0 = w2 + (size_t)e * IDIM * H_ + (size_t)(q * 8) * H_
                          + (size_t)nb0 * 16 + r;
    const float* pB1 = pB0 + 16;

    f32x4 acc[4][2] = {};
    uint4 ar0a, ar0b, ar1a, ar1b;
    bf16x8 bA0[2], bB0[2], bA1[2], bB1[2];   // [nf][kc] buffers x2 stages

#define LOADA(A0, A1) do { \
    A0 = *(const uint4*)pA; A1 = *(const uint4*)(pA + 8); pA += 64; } while (0)
#define STAGEA(A0, A1) do { \
    *(uint4*)wr0 = A0; *(uint4*)wr1 = A1; } while (0)
#define LOADB(B0, B1) do { \
    _Pragma("unroll") \
    for (int j = 0; j < 8; ++j) { \
        B0[0][j] = (bf16)pB0[(size_t)j * H_]; \
        B0[1][j] = (bf16)pB0[(size_t)(j + 32) * H_]; \
        B1[0][j] = (bf16)pB1[(size_t)j * H_]; \
        B1[1][j] = (bf16)pB1[(size_t)(j + 32) * H_]; \
    } \
    pB0 += 64 * H_; pB1 += 64 * H_; } while (0)
#define COMPUTE(B0, B1) do { \
    _Pragma("unroll") \
    for (int kc = 0; kc < 2; ++kc) { \
        bf16x8 afr[4]; \
        _Pragma("unroll") \
        for (int mf = 0; mf < 4; ++mf) \
            afr[mf] = *(const bf16x8*)(As + ((size_t)((mf * 2 + kc) * 64 + lane)) * 8); \
        _Pragma("unroll") \
        for (int mf = 0; mf < 4; ++mf) { \
            acc[mf][0] = __builtin_amdgcn_mfma_f32_16x16x32_bf16(afr[mf], B0[kc], acc[mf][0], 0, 0, 0); \
            acc[mf][1] = __builtin_amdgcn_mfma_f32_16x16x32_bf16(afr[mf], B1[kc], acc[mf][1], 0, 0, 0); \
        } \
    } } while (0)

    LOADA(ar0a, ar0b);
    LOADB(bA0, bB0);
    #pragma unroll 1
    for (int kb = 0; kb < 14; kb += 2) {
        __syncthreads();
        STAGEA(ar0a, ar0b);
        LOADA(ar1a, ar1b);
        LOADB(bA1, bB1);
        __syncthreads();
        COMPUTE(bA0, bB0);

        __syncthreads();
        STAGEA(ar1a, ar1b);
        LOADA(ar0a, ar0b);
        LOADB(bA0, bB0);
        __syncthreads();
        COMPUTE(bA1, bB1);
    }
    // peeled final two k-steps: no out-of-bounds prefetch
    __syncthreads();
    STAGEA(ar0a, ar0b);
    LOADA(ar1a, ar1b);
    LOADB(bA1, bB1);
    __syncthreads();
    COMPUTE(bA0, bB0);

    __syncthreads();
    STAGEA(ar1a, ar1b);
    __syncthreads();
    COMPUTE(bA1, bB1);
#undef LOADA
#undef STAGEA
#undef LOADB
#undef COMPUTE

    #pragma unroll
    for (int nf = 0; nf < 2; ++nf) {
        const int ch = (nb0 + nf) * 16 + r;
        const float bb = b2[e * H_ + ch];
        #pragma unroll
        for (int mf = 0; mf < 4; ++mf) {
            #pragma unroll
            for (int rg = 0; rg < 4; ++rg) {
                const int row = mf * 16 + q * 4 + rg;
                const int s = m0 + row;
                if (s < ne) {
                    const int   tok = tok_list[e * T_ + s];
                    const float w   = wgt_list[e * T_ + s];
                    atomicAdd(&out[(size_t)tok * H_ + ch], w * (acc[mf][nf][rg] + bb));
                }
            }
        }
    }
}

// ---------------------------------------------------------------------------
// Fallback (round-1) GEMMs, used if ws too small for routing metadata + act.
// ---------------------------------------------------------------------------
__global__ __launch_bounds__(256) void k_gateup(
    const bf16* __restrict__ tB, const float* __restrict__ w13,
    const float* __restrict__ b13, const int* __restrict__ cnt,
    const int* __restrict__ base, const int* __restrict__ tok_list,
    bf16* __restrict__ act)
{
    const int e  = blockIdx.z;
    const int ne = cnt[e];
    const int m0 = blockIdx.y * 64;
    if (m0 >= ne) return;
    const int n0  = blockIdx.x * 64;
    const int tid = threadIdx.x, lane = tid & 63, wave = tid >> 6;

    __shared__ __align__(16) bf16 As[64][40];
    __shared__ __align__(16) bf16 Bg[64][40];
    __shared__ __align__(16) bf16 Bu[64][40];
    __shared__ int stok[64];

    if (tid < 64) {
        const int s = m0 + tid;
        stok[tid] = (s < ne) ? tok_list[e * T_ + s] : -1;
    }
    __syncthreads();

    const int ar = tid >> 2, ak = (tid & 3) * 8;
    const int atok = stok[ar];
    const int bn = tid & 63, bk = wave * 8;
    const size_t wrow = (size_t)(2 * IDIM);
    const float* wbase = w13 + (size_t)e * H_ * wrow + n0 + bn;

    const int wm = wave >> 1, wn = wave & 1;
    const int q = lane >> 4, r = lane & 15;
    f32x4 accg[2][2] = {};
    f32x4 accu[2][2] = {};

    for (int kb = 0; kb < H_ / 32; ++kb) {
        __syncthreads();
        uint4 av = make_uint4(0u, 0u, 0u, 0u);
        if (atok >= 0)
            av = *(const uint4*)(tB + (size_t)atok * H_ + kb * 32 + ak);
        *(uint4*)&As[ar][ak] = av;
        {
            const float* src = wbase + (size_t)(kb * 32 + bk) * wrow;
            bf16x8 pg, pu;
            #pragma unroll
            for (int j = 0; j < 8; ++j) {
                pg[j] = (bf16)src[(size_t)j * wrow];
                pu[j] = (bf16)src[(size_t)j * wrow + IDIM];
            }
            *(bf16x8*)&Bg[bn][bk] = pg;
            *(bf16x8*)&Bu[bn][bk] = pu;
        }
        __syncthreads();
        bf16x8 a[2], bg[2], bu[2];
        a[0]  = *(const bf16x8*)&As[wm * 32 +      r][q * 8];
        a[1]  = *(const bf16x8*)&As[wm * 32 + 16 + r][q * 8];
        bg[0] = *(const bf16x8*)&Bg[wn * 32 +      r][q * 8];
        bg[1] = *(const bf16x8*)&Bg[wn * 32 + 16 + r][q * 8];
        bu[0] = *(const bf16x8*)&Bu[wn * 32 +      r][q * 8];
        bu[1] = *(const bf16x8*)&Bu[wn * 32 + 16 + r][q * 8];
        #pragma unroll
        for (int im = 0; im < 2; ++im)
            #pragma unroll
            for (int in = 0; in < 2; ++in) {
                accg[im][in] = __builtin_amdgcn_mfma_f32_16x16x32_bf16(a[im], bg[in], accg[im][in], 0, 0, 0);
                accu[im][in] = __builtin_amdgcn_mfma_f32_16x16x32_bf16(a[im], bu[in], accu[im][in], 0, 0, 0);
            }
    }

    const int sb = base[e];
    #pragma unroll
    for (int im = 0; im < 2; ++im)
        #pragma unroll
        for (int in = 0; in < 2; ++in)
            #pragma unroll
            for (int rg = 0; rg < 4; ++rg) {
                const int row = wm * 32 + im * 16 + q * 4 + rg;
                const int col = wn * 32 + in * 16 + r;
                if (m0 + row < ne) {
                    const float hg = accg[im][in][rg] + b13[e * 2 * IDIM + n0 + col];
                    const float hu = accu[im][in][rg] + b13[e * 2 * IDIM + IDIM + n0 + col];
                    const float gt = fminf(hg, LIMIT);
                    const float up = fminf(fmaxf(hu, -LIMIT), LIMIT);
                    const float av = (up + 1.0f) * gt / (1.0f + expf(-ALPHA * gt));
                    act[(size_t)(sb + m0 + row) * IDIM + n0 + col] = (bf16)av;
                }
            }
}

__global__ __launch_bounds__(256) void k_down(
    const bf16* __restrict__ act, const float* __restrict__ w2,
    const float* __restrict__ b2, const int* __restrict__ cnt,
    const int* __restrict__ base, const int* __restrict__ tok_list,
    const float* __restrict__ wgt_list, float* __restrict__ out)
{
    const int e  = blockIdx.z;
    const int ne = cnt[e];
    const int m0 = blockIdx.y * 64;
    if (m0 >= ne) return;
    const int n0  = blockIdx.x * 64;
    const int tid = threadIdx.x, lane = tid & 63, wave = tid >> 6;

    __shared__ __align__(16) bf16 As[64][40];
    __shared__ __align__(16) bf16 Bs[64][40];
    __shared__ int   stok[64];
    __shared__ float swgt[64];

    if (tid < 64) {
        const int s = m0 + tid;
        stok[tid] = (s < ne) ? tok_list[e * T_ + s] : -1;
        swgt[tid] = (s < ne) ? wgt_list[e * T_ + s] : 0.f;
    }
    __syncthreads();

    const int sb = base[e];
    const int ar = tid >> 2, ak = (tid & 3) * 8;
    const bool arow_ok = (m0 + ar) < ne;
    const int bn = tid & 63, bk = wave * 8;
    const float* wbase = w2 + (size_t)e * IDIM * H_ + n0 + bn;

    const int wm = wave >> 1, wn = wave & 1;
    const int q = lane >> 4, r = lane & 15;
    f32x4 acc[2][2] = {};

    for (int kb = 0; kb < IDIM / 32; ++kb) {
        __syncthreads();
        uint4 av = make_uint4(0u, 0u, 0u, 0u);
        if (arow_ok)
            av = *(const uint4*)(act + (size_t)(sb + m0 + ar) * IDIM + kb * 32 + ak);
        *(uint4*)&As[ar][ak] = av;
        {
            const float* src = wbase + (size_t)(kb * 32 + bk) * H_;
            bf16x8 pb;
            #pragma unroll
            for (int j = 0; j < 8; ++j) pb[j] = (bf16)src[(size_t)j * H_];
            *(bf16x8*)&Bs[bn][bk] = pb;
        }
        __syncthreads();
        bf16x8 a[2], b[2];
        a[0] = *(const bf16x8*)&As[wm * 32 +      r][q * 8];
        a[1] = *(const bf16x8*)&As[wm * 32 + 16 + r][q * 8];
        b[0] = *(const bf16x8*)&Bs[wn * 32 +      r][q * 8];
        b[1] = *(const bf16x8*)&Bs[wn * 32 + 16 + r][q * 8];
        #pragma unroll
        for (int im = 0; im < 2; ++im)
            #pragma unroll
            for (int in = 0; in < 2; ++in)
                acc[im][in] = __builtin_amdgcn_mfma_f32_16x16x32_bf16(a[im], b[in], acc[im][in], 0, 0, 0);
    }

    #pragma unroll
    for (int im = 0; im < 2; ++im)
        #pragma unroll
        for (int in = 0; in < 2; ++in)
            #pragma unroll
            for (int rg = 0; rg < 4; ++rg) {
                const int row = wm * 32 + im * 16 + q * 4 + rg;
                const int col = wn * 32 + in * 16 + r;
                if (m0 + row < ne) {
                    const int   tok = stok[row];
                    const float w   = swgt[row];
                    atomicAdd(&out[(size_t)tok * H_ + n0 + col], w * (acc[im][in][rg] + b2[e * H_ + n0 + col]));
                }
            }
}

// ---------------------------------------------------------------------------
extern "C" void kernel_launch(void* const* d_in, const int* in_sizes, int n_in,
                              void* d_out, int out_size, void* d_ws, size_t ws_size,
                              hipStream_t stream)
{
    const float* x        = (const float*)d_in[0];
    const float* norm_w   = (const float*)d_in[1];
    const float* router_w = (const float*)d_in[2];
    const float* router_b = (const float*)d_in[3];
    const float* w13      = (const float*)d_in[4];
    const float* b13      = (const float*)d_in[5];
    const float* w2       = (const float*)d_in[6];
    const float* b2       = (const float*)d_in[7];
    const float* manual_w = (const float*)d_in[8];
    const int*   layer_i  = (const int*)d_in[9];
    float* out = (float*)d_out;

    char* ws = (char*)d_ws;
    bf16*  tB   = (bf16*)ws;                              // 2 MB @ 0
    bf16*  act  = (bf16*)(ws + (2ull << 20));             // 8 MB @ 2M
    char*  meta = ws + (10ull << 20);
    int*   cnt      = (int*)meta;                         // 16 ints
    int*   basep    = (int*)(meta + 64);                  // 17 ints
    int*   tiln     = (int*)(meta + 256);                 // 1 int
    int*   tile_e   = (int*)(meta + 512);                 // 96 ints
    int*   tile_m0  = (int*)(meta + 1024);                // 96 ints
    int*   tok_list = (int*)(meta + (16ull << 10));       // 64 KB
    float* wgt_list = (float*)(meta + (16ull << 10) + (64ull << 10)); // 64 KB

    const bool fast = ws_size >= (11ull << 20);

    hipMemsetAsync(cnt, 0, E_ * sizeof(int), stream);

    k_rms_router<<<T_, 256, 0, stream>>>(x, norm_w, router_w, router_b,
                                         manual_w, layer_i, tB, out,
                                         cnt, tok_list, wgt_list);
    k_scan<<<1, 64, 0, stream>>>(cnt, basep, tiln, tile_e, tile_m0);

    if (fast) {
        dim3 gg(16, 80);
        k_gateup4<<<gg, 256, 0, stream>>>(tB, w13, b13, cnt, basep, tiln,
                                          tile_e, tile_m0, tok_list, act);
        dim3 gd(8, 80);
        k_down4<<<gd, 256, 0, stream>>>(act, w2, b2, cnt, basep, tiln,
                                        tile_e, tile_m0, tok_list, wgt_list, out);
    } else {
        dim3 gg(IDIM / 64, T_ / 64, E_);
        k_gateup<<<gg, 256, 0, stream>>>(tB, w13, b13, cnt, basep, tok_list, act);
        dim3 gd(H_ / 64, T_ / 64, E_);
        k_down<<<gd, 256, 0, stream>>>(act, w2, b2, cnt, basep, tok_list, wgt_list, out);
    }
}